// Round 4
// baseline (1692.710 us; speedup 1.0000x reference)
//
#include <hip/hip_runtime.h>
#include <hip/hip_bf16.h>

// ---- static problem config ----
constexpr int B_    = 8;
constexpr int L1_   = 7;
constexpr int L2_   = 3;
constexpr int N1_   = 2048;
constexpr int N2_   = 512;
constexpr int CIN_  = 512;
constexpr int MID_  = 256;
constexpr int OUT_  = 512;
constexpr int CORIG_= 128;
constexpr int K_    = 3;
constexpr int TFC_  = K_ * MID_;   // 768
constexpr int CTOT_ = MID_ + CORIG_; // 384

// -------------------------------------------------------------------------
// Kernel 1: temporal 1x1 conv -> tf[b][l2][o][n2], o in [0,768)
// C = Wt (768x512) x features[b,l2] (512x512)
// -------------------------------------------------------------------------
__global__ __launch_bounds__(256) void tconv_gemm(const float* __restrict__ feat,
                                                  const float* __restrict__ Wt,
                                                  float* __restrict__ tf)
{
    __shared__ float As[16][64];   // As[j][i] = Wt[o0+i][kk+j]
    __shared__ float Bs[16][68];   // Bs[j][i] = feat[kk+j][n0+i]
    const int tid = threadIdx.x;
    const int n0 = blockIdx.x * 64;
    const int o0 = blockIdx.y * 64;
    const int batch = blockIdx.z;          // b*L2 + l2
    const float* Bp = feat + (size_t)batch * CIN_ * N2_;
    float acc[4][4] = {};
    const int tx = tid & 15, ty = tid >> 4;
    for (int kk = 0; kk < CIN_; kk += 16) {
        #pragma unroll
        for (int r = 0; r < 4; r++) {
            int e = tid + r * 256;
            int i = e >> 4, j = e & 15;
            As[j][i] = Wt[(size_t)(o0 + i) * CIN_ + kk + j];
        }
        #pragma unroll
        for (int r = 0; r < 4; r++) {
            int e = tid + r * 256;
            int j = e >> 6, i = e & 63;
            Bs[j][i] = Bp[(size_t)(kk + j) * N2_ + n0 + i];
        }
        __syncthreads();
        #pragma unroll
        for (int j = 0; j < 16; j++) {
            float a[4], bb[4];
            #pragma unroll
            for (int r = 0; r < 4; r++) a[r] = As[j][ty * 4 + r];
            #pragma unroll
            for (int c = 0; c < 4; c++) bb[c] = Bs[j][tx * 4 + c];
            #pragma unroll
            for (int r = 0; r < 4; r++)
                #pragma unroll
                for (int c = 0; c < 4; c++)
                    acc[r][c] += a[r] * bb[c];
        }
        __syncthreads();
    }
    float* Cp = tf + (size_t)batch * TFC_ * N2_;
    #pragma unroll
    for (int r = 0; r < 4; r++)
        #pragma unroll
        for (int c = 0; c < 4; c++)
            Cp[(size_t)(o0 + ty * 4 + r) * N2_ + n0 + tx * 4 + c] = acc[r][c];
}

// -------------------------------------------------------------------------
// Kernel 2: BN statistics per channel-slice ch = l2*768 + o (2304 blocks)
// -------------------------------------------------------------------------
__global__ __launch_bounds__(256) void bn_stats(const float* __restrict__ tf,
                                                const float* __restrict__ gamma,
                                                const float* __restrict__ beta,
                                                float* __restrict__ scale,
                                                float* __restrict__ shift)
{
    const int ch = blockIdx.x;          // l2*TFC_ + o
    const int l2 = ch / TFC_;
    const int o  = ch % TFC_;
    const int mid = o % MID_;           // channel index within MID for gamma/beta
    const int tid = threadIdx.x;
    float s = 0.f, sq = 0.f;
    #pragma unroll
    for (int t = 0; t < 16; t++) {
        int v = tid + t * 256;          // 0..4095
        int b = v >> 9, n2 = v & 511;
        float x = tf[((size_t)(b * L2_ + l2) * TFC_ + o) * N2_ + n2];
        s += x; sq += x * x;
    }
    __shared__ float ss[256], sqs[256];
    ss[tid] = s; sqs[tid] = sq;
    __syncthreads();
    for (int st = 128; st > 0; st >>= 1) {
        if (tid < st) { ss[tid] += ss[tid + st]; sqs[tid] += sqs[tid + st]; }
        __syncthreads();
    }
    if (tid == 0) {
        float mean = ss[0] * (1.f / 4096.f);
        float var = fmaxf(sqs[0] * (1.f / 4096.f) - mean * mean, 0.f);
        float sc = gamma[mid] * rsqrtf(var + 1e-5f);
        scale[ch] = sc;
        shift[ch] = beta[mid] - mean * sc;
    }
}

// -------------------------------------------------------------------------
// Kernel 3: apply BN + ReLU in place on tf (9437184 elements)
// -------------------------------------------------------------------------
__global__ __launch_bounds__(256) void bn_apply(float* __restrict__ tf,
                                                const float* __restrict__ scale,
                                                const float* __restrict__ shift)
{
    int idx = blockIdx.x * 256 + threadIdx.x;
    int ch = (idx >> 9) % (L2_ * TFC_);
    float x = tf[idx];
    tf[idx] = fmaxf(x * scale[ch] + shift[ch], 0.f);
}

// -------------------------------------------------------------------------
// Kernel 4: 3-NN search + weights.
// Replicates the XLA:CPU fp32 arithmetic of the reference:
//   d2 = (|a|^2 + |n|^2) - 2*dot,  dot via Eigen-style ASCENDING FMA CHAIN
//   dot = fma(az*nz, fma(ay*ny, rn(ax*nx)))   <- the one free rounding choice
// norms/reduce and elementwise combine are separate per-op-rounded fp32 (HLO
// semantics). Only the top-3 SET matters (weighted sum is order-invariant),
// and the set is decided by these exact roundings at the 3rd/4th boundary.
// History: exact f64 selection -> absmax 0.566; no-FMA expanded -> 0.651.
// -------------------------------------------------------------------------
__global__ __launch_bounds__(256) void three_nn_kernel(const float* __restrict__ xyzs,
                                                       const float* __restrict__ oxyzs,
                                                       int* __restrict__ fbbuf,
                                                       float* __restrict__ wbuf)
{
    // temporal transpose gather table (t1 0-based)
    const int nsegs[7]  = {1, 1, 2, 1, 2, 1, 1};
    const int t2s[7][2] = {{0,0},{0,0},{0,1},{1,1},{1,2},{2,2},{2,2}};
    const int kks[7][2] = {{0,0},{1,1},{2,0},{1,1},{2,0},{1,1},{2,2}};

    const int tid = threadIdx.x;
    const int t1 = blockIdx.y;
    const int b  = blockIdx.z;
    const int M = nsegs[t1] * N2_;

    __shared__ float sx[1024], sy[1024], sz[1024], sn2[1024];
    for (int j = tid; j < M; j += 256) {
        int seg = j >> 9;
        int t2 = t2s[t1][seg];
        const float* p = xyzs + ((size_t)(b * L2_ + t2) * N2_ + (j & 511)) * 3;
        float x = p[0], y = p[1], z = p[2];
        sx[j] = x; sy[j] = y; sz[j] = z;
        // |n|^2 = ((x*x + y*y) + z*z), each op rounded fp32, no FMA (XLA reduce)
        sn2[j] = __fadd_rn(__fadd_rn(__fmul_rn(x, x), __fmul_rn(y, y)),
                           __fmul_rn(z, z));
    }
    __syncthreads();

    const int n1 = blockIdx.x * 256 + tid;
    const float* a = oxyzs + ((size_t)(b * L1_ + t1) * N1_ + n1) * 3;
    const float ax = a[0], ay = a[1], az = a[2];
    const float an2 = __fadd_rn(__fadd_rn(__fmul_rn(ax, ax), __fmul_rn(ay, ay)),
                                __fmul_rn(az, az));

    float d0 = 1e30f, d1 = 1e30f, d2v = 1e30f;
    int i0 = 0, i1 = 0, i2 = 0;
    for (int j = 0; j < M; j++) {
        // Eigen gemm K-loop: acc=0; acc=fma(a_k,b_k,acc) ascending ->
        // dot = rn(az*nz + rn(ay*ny + rn(ax*nx)))
        float dot = fmaf(az, sz[j], fmaf(ay, sy[j], __fmul_rn(ax, sx[j])));
        // d2 = (an2 + nn2) - rn(2*dot), separate HLO roundings
        float d = __fsub_rn(__fadd_rn(an2, sn2[j]), __fmul_rn(2.0f, dot));
        // stable ascending insertion (ties keep lower index) == top_k(-d2,3)
        if (d < d0)       { d2v = d1; i2 = i1; d1 = d0; i1 = i0; d0 = d; i0 = j; }
        else if (d < d1)  { d2v = d1; i2 = i1; d1 = d;  i1 = j; }
        else if (d < d2v) { d2v = d;  i2 = j; }
    }
    // dist = sqrt(max(d2, 1e-12)); w = 1/(dist + 1e-8); w /= sum(w)  — fp32
    float dist0 = sqrtf(fmaxf(d0,  1e-12f));
    float dist1 = sqrtf(fmaxf(d1,  1e-12f));
    float dist2 = sqrtf(fmaxf(d2v, 1e-12f));
    float w0 = 1.0f / __fadd_rn(dist0, 1e-8f);
    float w1 = 1.0f / __fadd_rn(dist1, 1e-8f);
    float w2 = 1.0f / __fadd_rn(dist2, 1e-8f);
    float wsum = __fadd_rn(__fadd_rn(w0, w1), w2);
    w0 = w0 / wsum; w1 = w1 / wsum; w2 = w2 / wsum;

    size_t base = ((size_t)(b * L1_ + t1) * N1_ + n1) * 3;
    int   idxs[3] = {i0, i1, i2};
    float wws[3]  = {w0, w1, w2};
    #pragma unroll
    for (int j = 0; j < 3; j++) {
        int seg = idxs[j] >> 9;
        int t2 = t2s[t1][seg];
        int k  = kks[t1][seg];
        fbbuf[base + j] = ((b * L2_ + t2) * K_ + k) * (MID_ * N2_) + (idxs[j] & 511);
        wbuf[base + j]  = wws[j];
    }
}

// -------------------------------------------------------------------------
// Kernel 5: spatial 1x1 conv with fused 3-NN gather + concat.
// Per (b,t1): C(512x2048) = Ws(512x384) x nf(384x2048),
// nf rows 0..255 gathered from sf via (fb, w), rows 256..383 from orig feats.
// -------------------------------------------------------------------------
__global__ __launch_bounds__(256) void sconv_gemm(const float* __restrict__ sf,
                                                  const float* __restrict__ of,
                                                  const float* __restrict__ Ws,
                                                  const int* __restrict__ fbbuf,
                                                  const float* __restrict__ wbuf,
                                                  float* __restrict__ outp)
{
    __shared__ float As[16][64];
    __shared__ float Bs[16][68];
    __shared__ int   sFB[192];
    __shared__ float sW[192];
    const int tid = threadIdx.x;
    const int n0 = blockIdx.x * 64;
    const int o0 = blockIdx.y * 64;
    const int bt = blockIdx.z;             // b*L1 + t1

    if (tid < 192) {
        size_t gbase = ((size_t)bt * N1_ + n0) * 3;
        sFB[tid] = fbbuf[gbase + tid];
        sW[tid]  = wbuf [gbase + tid];
    }
    __syncthreads();

    float acc[4][4] = {};
    const int tx = tid & 15, ty = tid >> 4;
    const float* ofp = of + (size_t)bt * CORIG_ * N1_;

    for (int kk = 0; kk < CTOT_; kk += 16) {
        #pragma unroll
        for (int r = 0; r < 4; r++) {
            int e = tid + r * 256;
            int i = e >> 4, j = e & 15;
            As[j][i] = Ws[(size_t)(o0 + i) * CTOT_ + kk + j];
        }
        #pragma unroll
        for (int r = 0; r < 4; r++) {
            int e = tid + r * 256;
            int j = e >> 6, i = e & 63;
            int c = kk + j;
            float v;
            if (c < MID_) {
                int gb = i * 3;
                size_t co = (size_t)c * N2_;
                v = sW[gb]     * sf[(size_t)sFB[gb]     + co]
                  + sW[gb + 1] * sf[(size_t)sFB[gb + 1] + co]
                  + sW[gb + 2] * sf[(size_t)sFB[gb + 2] + co];
            } else {
                v = ofp[(size_t)(c - MID_) * N1_ + n0 + i];
            }
            Bs[j][i] = v;
        }
        __syncthreads();
        #pragma unroll
        for (int j = 0; j < 16; j++) {
            float a[4], bb[4];
            #pragma unroll
            for (int r = 0; r < 4; r++) a[r] = As[j][ty * 4 + r];
            #pragma unroll
            for (int c = 0; c < 4; c++) bb[c] = Bs[j][tx * 4 + c];
            #pragma unroll
            for (int r = 0; r < 4; r++)
                #pragma unroll
                for (int c = 0; c < 4; c++)
                    acc[r][c] += a[r] * bb[c];
        }
        __syncthreads();
    }
    float* Cp = outp + (size_t)bt * OUT_ * N1_;
    #pragma unroll
    for (int r = 0; r < 4; r++)
        #pragma unroll
        for (int c = 0; c < 4; c++)
            Cp[(size_t)(o0 + ty * 4 + r) * N1_ + n0 + tx * 4 + c] = acc[r][c];
}

// -------------------------------------------------------------------------
extern "C" void kernel_launch(void* const* d_in, const int* in_sizes, int n_in,
                              void* d_out, int out_size, void* d_ws, size_t ws_size,
                              hipStream_t stream)
{
    const float* xyzs  = (const float*)d_in[0];  // (B, L2, N2, 3)
    const float* oxyzs = (const float*)d_in[1];  // (B, L1, N1, 3)
    const float* feats = (const float*)d_in[2];  // (B, L2, CIN, N2)
    const float* ofeat = (const float*)d_in[3];  // (B, L1, CORIG, N1)
    const float* Wt    = (const float*)d_in[4];  // (768, 512)
    const float* gamma = (const float*)d_in[5];  // (256,)
    const float* beta  = (const float*)d_in[6];  // (256,)
    const float* Ws    = (const float*)d_in[7];  // (512, 384)
    float* out = (float*)d_out;

    // workspace layout
    char* ws = (char*)d_ws;
    float* tf    = (float*)ws;                                   // 9437184 f = 37748736 B
    float* scale = (float*)(ws + 37748736);                      // 2304 f
    float* shift = scale + 2304;                                 // 2304 f
    int*   fbbuf = (int*)(ws + 37748736 + 18432);                // 344064 i
    float* wbuf  = (float*)(ws + 37748736 + 18432 + 1376256);    // 344064 f

    // Output 0: original_xyzs passthrough
    hipMemcpyAsync(out, oxyzs, (size_t)B_ * L1_ * N1_ * 3 * sizeof(float),
                   hipMemcpyDeviceToDevice, stream);
    float* out_nf = out + (size_t)B_ * L1_ * N1_ * 3;

    tconv_gemm<<<dim3(N2_ / 64, TFC_ / 64, B_ * L2_), 256, 0, stream>>>(feats, Wt, tf);
    bn_stats<<<L2_ * TFC_, 256, 0, stream>>>(tf, gamma, beta, scale, shift);
    bn_apply<<<(B_ * L2_ * TFC_ * N2_) / 256, 256, 0, stream>>>(tf, scale, shift);
    three_nn_kernel<<<dim3(N1_ / 256, L1_, B_), 256, 0, stream>>>(xyzs, oxyzs, fbbuf, wbuf);
    sconv_gemm<<<dim3(N1_ / 64, OUT_ / 64, B_ * L1_), 256, 0, stream>>>(tf, ofeat, Ws, fbbuf, wbuf, out_nf);
}